// Round 5
// baseline (410.661 us; speedup 1.0000x reference)
//
#include <hip/hip_runtime.h>
#include <hip/hip_cooperative_groups.h>
#include <math.h>

namespace cg = cooperative_groups;

typedef unsigned int u32;
typedef unsigned short u16;
typedef unsigned long long u64;

#define PRE_NMS 6000
#define NBLK    94          /* ceil(6000/64) rank-bitmap words */
#define KMAX    640         /* group capacity (E[K]~375) */
#define MSTRIDE 11          /* mask row stride, > KMAX/64 */
#define MAXW    10          /* max 64-blocks per group */
#define FINEB   8192        /* [0.5,1) buckets, 2^10 ulp each */
#define LOWB    8064        /* [0,0.5) buckets, bits>>17 */
#define CANDMAX 16384
#define NGRP    24
#define CBUF    512         /* per-block compact staging (E~24/block) */
#define NBLOCKS 256
#define NTHREADS 256
#define NTOT    (NBLOCKS * NTHREADS)
#define FLOOR_BITS 0x3F000000u   /* 0.5f */

/* ws byte offsets */
#define CTR_OFF    0          /* 64 u32 */
#define CAND_OFF   256        /* 16384 u64 -> 131328 */
#define BOXR_OFF   131328     /* 6016 float4 -> 227584 */
#define GBITS_OFF  227584     /* 24*192 u32 -> 246016 */
#define KG_OFF     246016     /* 64 u32 -> 246272 */
#define GRANKG_OFF 246272     /* 24*640 u32 -> 307712 */
#define BOXG_OFF   307712     /* 24*640 float4 -> 553472 */
#define AREAG_OFF  553472     /* 24*640 f32 -> 614912 */
#define MASKG_OFF  614912     /* 24*640*11 u64 -> 1966592 */
#define FINEH_OFF  1966592    /* 8192 u32 -> 1999360 */
#define LOWP_OFF   1999360    /* 256*8064 u32 -> 10256896 */

/* One cooperative kernel: 8 former launches as phases.
   P0 zero | P1 hist | P2 pivot | P3 compact | P4 rank+decode
   P5 prep | P6 mask | P7 greedy.  All blocks reach all grid.sync()s. */
__global__ __launch_bounds__(NTHREADS) void mega_kernel(
    const float4* __restrict__ probs4,
    const float4* __restrict__ deltas4,
    const float4* __restrict__ anchors4,
    float* __restrict__ out,
    char* __restrict__ ws,
    int n_prop, int n_anch)
{
    cg::grid_group grid = cg::this_grid();

    u32*    ctr    = (u32*)(ws + CTR_OFF);
    u64*    cand   = (u64*)(ws + CAND_OFF);
    float4* boxr   = (float4*)(ws + BOXR_OFF);
    u32*    gbits  = (u32*)(ws + GBITS_OFF);
    u32*    kg     = (u32*)(ws + KG_OFF);
    u32*    grankg = (u32*)(ws + GRANKG_OFF);
    float4* boxg   = (float4*)(ws + BOXG_OFF);
    float*  areag  = (float*)(ws + AREAG_OFF);
    u64*    maskg  = (u64*)(ws + MASKG_OFF);
    u32*    fineh  = (u32*)(ws + FINEH_OFF);
    u32*    lowp   = (u32*)(ws + LOWP_OFF);

    __shared__ __align__(16) unsigned char pool[65024];   /* phase-aliased */
    __shared__ u32 s_cnt, s_base;
    __shared__ int s_K;

    const int t    = threadIdx.x;
    const int bid  = blockIdx.x;
    const int gtid = bid * NTHREADS + t;
    const int lane = t & 63, wv = t >> 6;

    /* ---- P0: zero global state ---- */
    for (int i = gtid; i < FINEB; i += NTOT) fineh[i] = 0u;
    if (gtid < 64) ctr[gtid] = 0u;
    for (int i = gtid; i < NGRP * 192; i += NTOT) gbits[i] = 0u;
    grid.sync();

    /* ---- P1: histogram (256 blocks; fine via sparse global atomics,
            low via per-block partials used only in fallback) ---- */
    {
        u32* hf = (u32*)pool;           /* 8192 */
        u32* hl = hf + FINEB;           /* 8064 */
        for (int i = t; i < FINEB + LOWB; i += NTHREADS) hf[i] = 0u;
        __syncthreads();
        int nq = n_prop >> 2;
        for (int q = gtid; q < nq; q += NTOT) {
            float4 a = probs4[3 * q + 0];
            float4 b = probs4[3 * q + 1];
            float4 c = probs4[3 * q + 2];
            float vs[8] = {a.y, a.z, b.x, b.y, b.w, c.x, c.z, c.w};
            #pragma unroll
            for (int e = 0; e < 8; ++e) {
                u32 bits = __float_as_uint(vs[e]);
                if (bits >= FLOOR_BITS) {
                    u32 fb = (bits - FLOOR_BITS) >> 10; if (fb >= FINEB) fb = FINEB - 1;
                    atomicAdd(&hf[fb], 1u);
                } else {
                    atomicAdd(&hl[bits >> 17], 1u);
                }
            }
        }
        __syncthreads();
        for (int i = t; i < FINEB; i += NTHREADS) {
            u32 v = hf[i];
            if (v) atomicAdd(&fineh[i], v);
        }
        u32* myLow = lowp + bid * LOWB;
        for (int i = t; i < LOWB; i += NTHREADS) myLow[i] = hl[i];
    }
    grid.sync();

    /* ---- P2: pivot scan (block 0 only; identical bucket semantics) ---- */
    if (bid == 0) {
        u32* fh = (u32*)pool;           /* 8192 */
        u32* sd = fh + FINEB;           /* 256  */
        for (int b = t; b < FINEB; b += NTHREADS) fh[b] = fineh[b];
        __syncthreads();
        int hi = FINEB - 1 - 32 * t;
        u32 L = 0;
        #pragma unroll
        for (int e = 0; e < 32; ++e) L += fh[hi - e];
        sd[t] = L;
        __syncthreads();
        for (int off = 1; off < NTHREADS; off <<= 1) {
            u32 x = (t >= off) ? sd[t - off] : 0u;
            __syncthreads();
            sd[t] += x;
            __syncthreads();
        }
        u32 incl = sd[t], excl = incl - L;
        u32 fineTotal = sd[NTHREADS - 1];
        if (excl < (u32)PRE_NMS && incl >= (u32)PRE_NMS) {
            u32 run = excl;
            for (int e = 0; e < 32; ++e) {
                u32 c = fh[hi - e];
                if (run < (u32)PRE_NMS && run + c >= (u32)PRE_NMS)
                    ctr[1] = FLOOR_BITS + ((u32)(hi - e) << 10);
                run += c;
            }
        }
        if (fineTotal < (u32)PRE_NMS) {
            /* fallback (never expected): reduce low partials, coarse pivot */
            u32 rem = (u32)PRE_NMS - fineTotal;
            __syncthreads();
            for (int b = t; b < FINEB; b += NTHREADS) {
                u32 s = 0;
                if (b < LOWB) {
                    for (int k = 0; k < NBLOCKS; ++k) s += lowp[k * LOWB + b];
                }
                fh[b] = s;
            }
            __syncthreads();
            L = 0;
            for (int e = 0; e < 32; ++e) L += fh[hi - e];
            sd[t] = L;
            __syncthreads();
            for (int off = 1; off < NTHREADS; off <<= 1) {
                u32 x = (t >= off) ? sd[t - off] : 0u;
                __syncthreads();
                sd[t] += x;
                __syncthreads();
            }
            incl = sd[t]; excl = incl - L;
            if (excl < rem && incl >= rem) {
                u32 run = excl;
                for (int e = 0; e < 32; ++e) {
                    u32 c = fh[hi - e];
                    if (run < rem && run + c >= rem)
                        ctr[1] = ((u32)(hi - e)) << 17;
                    run += c;
                }
            }
        }
    }
    grid.sync();

    /* ---- P3: compact (LDS staging, 1 global atomic per block) ---- */
    {
        u64* sloc = (u64*)pool;         /* 512 u64 */
        if (t == 0) s_cnt = 0u;
        __syncthreads();
        u32 pivot = ctr[1];
        int nq = n_prop >> 2;
        for (int q = gtid; q < nq; q += NTOT) {
            float4 a = probs4[3 * q + 0];
            float4 b = probs4[3 * q + 1];
            float4 c = probs4[3 * q + 2];
            float vs[8] = {a.y, a.z, b.x, b.y, b.w, c.x, c.z, c.w};
            #pragma unroll
            for (int e = 0; e < 8; ++e) {
                u32 bits = __float_as_uint(vs[e]);
                if (bits >= pivot) {
                    u32 lp = atomicAdd(&s_cnt, 1u);
                    u32 i = (u32)(8 * q + e);
                    if (lp < (u32)CBUF) sloc[lp] = ((u64)bits << 32) | (u64)(~i);
                }
            }
        }
        __syncthreads();
        u32 cnt = s_cnt; if (cnt > (u32)CBUF) cnt = (u32)CBUF;
        if (t == 0) s_base = atomicAdd(&ctr[0], cnt);
        __syncthreads();
        for (u32 j = t; j < cnt; j += NTHREADS) {
            u32 pos = s_base + j;
            if (pos < (u32)CANDMAX) cand[pos] = sloc[j];
        }
    }
    grid.sync();

    /* ---- P4: fused rank-by-counting + decode.  Each thread owns key i,
            counts greater keys via LDS tiles, then decodes in place. ---- */
    {
        u64* tile = (u64*)pool;         /* 2048 u64 = 16 KB */
        u32 M = ctr[0]; if (M > (u32)CANDMAX) M = (u32)CANDMAX;
        u32 i = (u32)gtid;
        u64 key = (i < M) ? cand[i] : 0ull;
        u32 cnt = 0;
        for (u32 base = 0; base < M; base += 2048) {
            for (u32 j = t; j < 2048; j += NTHREADS) {
                u32 idx = base + j;
                tile[j] = (idx < M) ? cand[idx] : 0ull;   /* 0-pad: real keys > 0 */
            }
            __syncthreads();
            #pragma unroll 8
            for (int q = 0; q < 2048; ++q) cnt += (tile[q] > key) ? 1u : 0u;
            __syncthreads();
        }
        if (i < M && cnt < (u32)PRE_NMS) {
            u32 r = cnt;
            u32 bits = (u32)(key >> 32);
            u32 flat = ~((u32)key);
            int p = (int)(flat >> 1);
            int cls = (int)(flat & 1u) + 1;
            int b = p / n_anch;
            int g = b * 3 + cls;
            int aidx = p - b * n_anch;
            float score = __uint_as_float(bits);
            float4 a = anchors4[aidx];
            float4 d = deltas4[p];
            float d0 = d.x * 0.1f, d1 = d.y * 0.1f, d2 = d.z * 0.2f, d3 = d.w * 0.2f;
            float y1 = a.x * (1.0f / 512.0f), x1 = a.y * (1.0f / 512.0f);
            float y2 = a.z * (1.0f / 512.0f), x2 = a.w * (1.0f / 512.0f);
            float h = y2 - y1, w = x2 - x1;
            float cy = y1 + 0.5f * h + d0 * h;
            float cx = x1 + 0.5f * w + d1 * w;
            h = h * expf(d2);
            w = w * expf(d3);
            float ry1 = (cy - 0.5f * h) * 512.0f;
            float rx1 = (cx - 0.5f * w) * 512.0f;
            float ry2 = (cy - 0.5f * h + h) * 512.0f;
            float rx2 = (cx - 0.5f * w + w) * 512.0f;
            ry1 = fminf(fmaxf(ry1, 0.0f), 512.0f);
            rx1 = fminf(fmaxf(rx1, 0.0f), 512.0f);
            ry2 = fminf(fmaxf(ry2, 0.0f), 512.0f);
            rx2 = fminf(fmaxf(rx2, 0.0f), 512.0f);
            out[r * 6 + 0] = ry1;
            out[r * 6 + 1] = rx1;
            out[r * 6 + 2] = ry2;
            out[r * 6 + 3] = rx2;
            out[r * 6 + 4] = score;
            out[r * 6 + 5] = 1.0f;               /* default keep; P7 overwrites */
            out[PRE_NMS * 6 + r] = (float)cls;
            out[PRE_NMS * 7 + r] = (float)b;
            boxr[r] = make_float4(ry1, rx1, ry2, rx2);
            atomicOr(&gbits[g * 192 + (r >> 5)], 1u << (r & 31));
        }
    }
    grid.sync();

    /* ---- P5: per-group prep: bitmap prefix -> rank-ordered box table ---- */
    {
        int* bpre   = (int*)pool;                /* 96 int  */
        u16* grankS = (u16*)(pool + 512);        /* 640 u16 */
        int g = bid;
        if (g < NGRP) {
            const u32* rb32 = gbits + g * 192;
            if (t < 64) {
                u64 w0 = (u64)rb32[2 * lane] | ((u64)rb32[2 * lane + 1] << 32);
                u64 w1 = (lane < NBLK - 64)
                         ? ((u64)rb32[128 + 2 * lane] | ((u64)rb32[129 + 2 * lane] << 32)) : 0ull;
                int c0 = (int)__popcll(w0), c1 = (int)__popcll(w1);
                int i0 = c0, i1 = c1;
                #pragma unroll
                for (int off = 1; off < 64; off <<= 1) {
                    int a = __shfl_up(i0, off); if (lane >= off) i0 += a;
                    int b = __shfl_up(i1, off); if (lane >= off) i1 += b;
                }
                int tot0 = __shfl(i0, 63), tot1 = __shfl(i1, 63);
                bpre[lane] = i0 - c0;
                if (lane < 32) bpre[64 + lane] = tot0 + ((lane < NBLK - 64) ? (i1 - c1) : 0);
                if (lane == 0) { s_K = tot0 + tot1; kg[g] = (u32)(tot0 + tot1); }
            }
            __syncthreads();
            int K = s_K;
            if (K > 0) {
                int Kc = (K < KMAX) ? K : KMAX;
                for (int blk = wv; blk < NBLK; blk += 4) {
                    u64 wmask = (u64)rb32[2 * blk] | ((u64)rb32[2 * blk + 1] << 32);
                    if ((wmask >> lane) & 1ull) {
                        int pos = bpre[blk] + (int)__popcll(wmask & ((1ull << lane) - 1ull));
                        if (pos < KMAX) grankS[pos] = (u16)((blk << 6) | lane);
                    }
                }
                __syncthreads();
                float4* bg = boxg + g * KMAX;
                float*  ag = areag + g * KMAX;
                u32*    gr = grankg + g * KMAX;
                for (int m = t; m < KMAX; m += NTHREADS) {
                    if (m < Kc) {
                        int r = grankS[m];
                        float4 bb = boxr[r];
                        bg[m] = bb;
                        ag[m] = (bb.z - bb.x + 1.0f) * (bb.w - bb.y + 1.0f);
                        gr[m] = (u32)r;
                    } else {
                        bg[m] = make_float4(-3e30f, -3e30f, -3e30f, -3e30f);
                        ag[m] = 3e38f;
                    }
                }
            }
        }
    }
    grid.sync();

    /* ---- P6: register-shuffle 64x64 IoU tiles over (group,c,rbk) units ---- */
    {
        int gw = bid * 4 + wv;                   /* 1024 wave slots */
        const int NUNIT = NGRP * MAXW * MAXW;
        for (int u = gw; u < NUNIT; u += NBLOCKS * 4) {
            int g = u / (MAXW * MAXW);
            int rm = u % (MAXW * MAXW);
            int c = rm / MAXW, rbk = rm % MAXW;
            u32 K = kg[g];
            if (K == 0u) continue;
            int Kc = (K < (u32)KMAX) ? (int)K : KMAX;
            int W = (Kc + 63) >> 6;
            if (c >= W || rbk >= W) continue;
            int r = rbk * 64 + lane;
            u64* mg = maskg + (size_t)g * (KMAX * MSTRIDE);
            if (rbk > c) { mg[r * MSTRIDE + c] = 0ull; continue; }
            int j0 = c << 6;
            const float4* bg = boxg + g * KMAX;
            const float*  ag = areag + g * KMAX;
            float4 rb = bg[r];
            float  ra = ag[r];
            float4 cb = bg[j0 + lane];
            float  ca = ag[j0 + lane];
            u64 word = 0ull;
            #pragma unroll 8
            for (int q = 0; q < 64; ++q) {
                float cbx = __shfl(cb.x, q);
                float cby = __shfl(cb.y, q);
                float cbz = __shfl(cb.z, q);
                float cbw = __shfl(cb.w, q);
                float cav = __shfl(ca, q);
                float ih = fminf(rb.z, cbz) - fmaxf(rb.x, cbx) + 1.0f;
                float iw = fminf(rb.w, cbw) - fmaxf(rb.y, cby) + 1.0f;
                ih = fmaxf(ih, 0.0f); iw = fmaxf(iw, 0.0f);
                /* iou>=0.5 <=> 3*inter >= ai+aj */
                bool o = (3.0f * ih * iw >= ra + cav) && ((j0 + q) > r);
                if (o) word |= (1ull << q);
            }
            mg[r * MSTRIDE + c] = word;
        }
    }
    grid.sync();

    /* ---- P7: per-group serial greedy (identical scan) ---- */
    {
        int g = bid;
        if (g < NGRP) {
            u32 K = kg[g];
            if (K > 0u) {
                u64* maskm = (u64*)pool;                 /* up to 7104 u64 */
                u16* grank = (u16*)(pool + 57344);       /* 640 u16 */
                int Kc = (K < (u32)KMAX) ? (int)K : KMAX;
                int W = (Kc + 63) >> 6;
                const u64* mg = maskg + (size_t)g * (KMAX * MSTRIDE);
                int nw = Kc * MSTRIDE;
                for (int m = t; m < nw; m += NTHREADS) maskm[m] = mg[m];
                for (int m = nw + t; m < nw + 64; m += NTHREADS) maskm[m] = 0ull;
                for (int m = t; m < Kc; m += NTHREADS) grank[m] = (u16)grankg[g * KMAX + m];
                __syncthreads();
                if (t < 64) {
                    u64 remv = 0ull;
                    for (int w = 0; w < W; ++w) {
                        int r0 = w << 6;
                        int rend = Kc - r0; if (rend > 64) rend = 64;
                        u64 curw = __shfl(remv, w);
                        u64 kb = 0ull;
                        for (int b0 = 0; b0 < rend; b0 += 8) {
                            int n = rend - b0; if (n > 8) n = 8;
                            u64 mrow[8], dg[8];
                            #pragma unroll
                            for (int j = 0; j < 8; ++j) {
                                int rr = r0 + b0 + ((j < n) ? j : 0);
                                mrow[j] = maskm[rr * MSTRIDE + lane];   /* +64 pad covers overrun */
                                dg[j]   = maskm[rr * MSTRIDE + w];      /* uniform: broadcast */
                            }
                            #pragma unroll
                            for (int j = 0; j < 8; ++j) {
                                if (j < n) {
                                    int b = b0 + j;
                                    u64 km = ((curw >> b) & 1ull) ? 0ull : ~0ull;
                                    curw |= dg[j] & km;
                                    remv |= mrow[j] & km;
                                    kb |= km & (1ull << b);
                                }
                            }
                        }
                        if (lane < rend)
                            out[(int)grank[r0 + lane] * 6 + 5] = ((kb >> lane) & 1ull) ? 1.0f : 0.0f;
                    }
                }
            }
        }
    }
}

extern "C" void kernel_launch(void* const* d_in, const int* in_sizes, int n_in,
                              void* d_out, int out_size, void* d_ws, size_t ws_size,
                              hipStream_t stream) {
    const float4* probs4   = (const float4*)d_in[0];
    const float4* deltas4  = (const float4*)d_in[1];
    const float4* anchors4 = (const float4*)d_in[2];
    int n_prop = in_sizes[1] / 4;   /* 522240 */
    int n_anch = in_sizes[2] / 4;   /* 65280  */
    char* ws   = (char*)d_ws;
    float* out = (float*)d_out;

    void* kargs[] = {
        (void*)&probs4, (void*)&deltas4, (void*)&anchors4,
        (void*)&out, (void*)&ws, (void*)&n_prop, (void*)&n_anch
    };
    hipLaunchCooperativeKernel((void*)mega_kernel, dim3(NBLOCKS), dim3(NTHREADS),
                               kargs, 0, stream);
}

// Round 6
// 209.630 us; speedup vs baseline: 1.9590x; 1.9590x over previous
//
#include <hip/hip_runtime.h>
#include <math.h>

typedef unsigned int u32;
typedef unsigned short u16;
typedef unsigned long long u64;

#define PRE_NMS 6000
#define NBLK    94          /* ceil(6000/64) rank-bitmap words */
#define KMAX    640         /* group capacity (E[K]~375) */
#define MSTRIDE 11          /* mask row stride, > KMAX/64 */
#define FINEB   8192        /* [0.5,1) buckets, 2^10 ulp each */
#define LOWB    8064        /* [0,0.5) buckets, bits>>17 */
#define TOTB    (FINEB + LOWB)
#define NHB     32          /* hist partial copies */
#define CANDMAX 16384
#define NGRP    24
#define FLOOR_BITS 0x3F000000u   /* 0.5f */

/* ws byte offsets */
#define CTR_OFF    0          /* 64 u32: [0]=M [1]=pivot bits */
#define CAND_OFF   256        /* 16384 u64 -> 131328 */
#define BOXR_OFF   131328     /* 6016 float4 -> 227584 */
#define GBITS_OFF  227584     /* 24*192 u32 -> 246016 */
#define KG_OFF     246016     /* 64 u32 -> 246272 */
#define GRANKG_OFF 246272     /* 24*640 u32 -> 307712 */
#define MASKG_OFF  307712     /* 24*640*11 u64 -> 1659392 */
#define BASE_OFF   1659392    /* 16384 u32 -> 1724928 */
#define BCNT_OFF   1724928    /* 16384 u32 -> 1790464 */
#define PART_OFF   1790464    /* 32 x 16256 u32 -> 3871232 */

/* bucket index in [0,16384): fine fb in [0,8192), low 8192+lb */
__device__ __forceinline__ u32 bucket_of(u32 bits) {
    if (bits >= FLOOR_BITS) {
        u32 fb = (bits - FLOOR_BITS) >> 10; if (fb > FINEB - 1) fb = FINEB - 1;
        return fb;
    }
    return 8192u + (bits >> 17);
}

/* 1: dual-range partial histograms (per-block copies, no pre-zero needed) */
__global__ __launch_bounds__(1024) void hist_kernel(const float4* __restrict__ probs4,
                                                    u32* __restrict__ partials, int n_prop) {
    __shared__ u32 hf[FINEB];      /* 32 KB */
    __shared__ u32 hl[2][LOWB];    /* 63 KB */
    int t = threadIdx.x;
    for (int i = t; i < FINEB; i += 1024) hf[i] = 0u;
    for (int i = t; i < 2 * LOWB; i += 1024) ((u32*)hl)[i] = 0u;
    __syncthreads();
    u32* l = hl[(t >> 6) & 1];
    int nq = n_prop >> 2;
    int idx = blockIdx.x * 1024 + t;
    int stride = gridDim.x * 1024;
    for (int q = idx; q < nq; q += stride) {
        float4 a = probs4[3 * q + 0];
        float4 b = probs4[3 * q + 1];
        float4 c = probs4[3 * q + 2];
        float vs[8] = {a.y, a.z, b.x, b.y, b.w, c.x, c.z, c.w};
        #pragma unroll
        for (int e = 0; e < 8; ++e) {
            u32 bits = __float_as_uint(vs[e]);
            if (bits >= FLOOR_BITS) {
                u32 fb = (bits - FLOOR_BITS) >> 10; if (fb >= FINEB) fb = FINEB - 1;
                atomicAdd(&hf[fb], 1u);
            } else {
                atomicAdd(&l[bits >> 17], 1u);
            }
        }
    }
    __syncthreads();
    u32* outp = partials + blockIdx.x * TOTB;
    for (int b = t; b < FINEB; b += 1024) outp[b] = hf[b];
    for (int b = t; b < LOWB; b += 1024) outp[FINEB + b] = hl[0][b] + hl[1][b];
}

/* 2: reduce partials, suffix-scan from top -> exact pivot + per-bucket base
   ranks (# keys in strictly-higher buckets); zero ctr/bcnt/gbits. */
__global__ __launch_bounds__(1024) void pivot_kernel(const u32* __restrict__ partials,
                                                     u32* __restrict__ ctr,
                                                     u32* __restrict__ base,
                                                     u32* __restrict__ bcnt,
                                                     u32* __restrict__ gbits) {
    __shared__ u32 fh[FINEB];
    __shared__ u32 sd[1024];
    int t = threadIdx.x;
    for (int i = t; i < 16384; i += 1024) bcnt[i] = 0u;
    for (int i = t; i < NGRP * 192; i += 1024) gbits[i] = 0u;
    if (t == 0) { ctr[0] = 0u; ctr[1] = 0u; }
    for (int b = t; b < FINEB; b += 1024) {
        u32 s = 0;
        #pragma unroll
        for (int k = 0; k < NHB; ++k) s += partials[k * TOTB + b];
        fh[b] = s;
    }
    __syncthreads();
    int hi = FINEB - 1 - 8 * t;
    u32 L = 0;
    #pragma unroll
    for (int e = 0; e < 8; ++e) L += fh[hi - e];
    sd[t] = L;
    __syncthreads();
    for (int off = 1; off < 1024; off <<= 1) {
        u32 x = (t >= off) ? sd[t - off] : 0u;
        __syncthreads();
        sd[t] += x;
        __syncthreads();
    }
    u32 incl = sd[t], excl = incl - L;
    u32 fineTotal = sd[1023];
    {
        u32 run = excl;
        #pragma unroll
        for (int e = 0; e < 8; ++e) {
            int fb = hi - e;
            base[fb] = run;
            u32 c = fh[fb];
            if (run < (u32)PRE_NMS && run + c >= (u32)PRE_NMS) {
                ctr[1] = FLOOR_BITS + ((u32)fb << 10);
                u32 m = run + c; if (m > (u32)CANDMAX) m = (u32)CANDMAX;
                ctr[0] = m;
            }
            run += c;
        }
    }
    if (fineTotal >= (u32)PRE_NMS) return;

    /* fallback (never expected): continue into [0, 0.5) coarse buckets */
    u32 rem = (u32)PRE_NMS - fineTotal;
    __syncthreads();
    for (int b = t; b < FINEB; b += 1024) {
        u32 s = 0;
        if (b < LOWB) {
            #pragma unroll
            for (int k = 0; k < NHB; ++k) s += partials[k * TOTB + FINEB + b];
        }
        fh[b] = s;
    }
    __syncthreads();
    L = 0;
    #pragma unroll
    for (int e = 0; e < 8; ++e) L += fh[hi - e];
    sd[t] = L;
    __syncthreads();
    for (int off = 1; off < 1024; off <<= 1) {
        u32 x = (t >= off) ? sd[t - off] : 0u;
        __syncthreads();
        sd[t] += x;
        __syncthreads();
    }
    incl = sd[t]; excl = incl - L;
    {
        u32 run = excl;
        #pragma unroll
        for (int e = 0; e < 8; ++e) {
            int lb = hi - e;
            base[8192 + lb] = fineTotal + run;
            u32 c = fh[lb];
            if (run < rem && run + c >= rem) {
                ctr[1] = ((u32)lb) << 17;
                u32 m = fineTotal + run + c; if (m > (u32)CANDMAX) m = (u32)CANDMAX;
                ctr[0] = m;
            }
            run += c;
        }
    }
}

/* 3: scatter-compact: candidate -> its bucket's contiguous slot range.
   Per-bucket atomics (contention <= bucket size ~ a few). */
__global__ __launch_bounds__(256) void scatter_kernel(const float4* __restrict__ probs4,
                                                      const u32* __restrict__ ctr,
                                                      const u32* __restrict__ base,
                                                      u32* __restrict__ bcnt,
                                                      u64* __restrict__ cand,
                                                      int n_prop) {
    u32 pivot = ctr[1];
    int nq = n_prop >> 2;
    int idx = blockIdx.x * 256 + threadIdx.x;
    int stride = gridDim.x * 256;
    for (int q = idx; q < nq; q += stride) {
        float4 a = probs4[3 * q + 0];
        float4 b = probs4[3 * q + 1];
        float4 c = probs4[3 * q + 2];
        float vs[8] = {a.y, a.z, b.x, b.y, b.w, c.x, c.z, c.w};
        #pragma unroll
        for (int e = 0; e < 8; ++e) {
            u32 bits = __float_as_uint(vs[e]);
            if (bits >= pivot) {
                u32 bk = bucket_of(bits);
                u32 off = atomicAdd(&bcnt[bk], 1u);
                u32 slot = base[bk] + off;
                u32 i = (u32)(8 * q + e);
                if (slot < (u32)CANDMAX) cand[slot] = ((u64)bits << 32) | (u64)(~i);
            }
        }
    }
}

/* 4: local rank (bucket base + count-greater among tiny bucket group) + decode.
   Writes det rows, rank-indexed box table, per-group rank bitmaps. */
__global__ __launch_bounds__(256) void rankdecode_kernel(const u64* __restrict__ cand,
                                                         const u32* __restrict__ ctr,
                                                         const u32* __restrict__ base,
                                                         const u32* __restrict__ bcnt,
                                                         const float4* __restrict__ deltas4,
                                                         const float4* __restrict__ anchors4,
                                                         float4* __restrict__ boxr,
                                                         u32* __restrict__ gbits,
                                                         float* __restrict__ out,
                                                         int n_anch) {
    u32 M = ctr[0]; if (M > (u32)CANDMAX) M = (u32)CANDMAX;
    u32 i = blockIdx.x * 256 + threadIdx.x;
    if (i >= M) return;
    u64 key = cand[i];
    u32 bits = (u32)(key >> 32);
    u32 bk = bucket_of(bits);
    u32 b0 = base[bk];
    u32 n = bcnt[bk];
    u32 r = b0;
    if (n > 1) {
        u32 end = b0 + n; if (end > M) end = M;
        u32 cnt = 0;
        for (u32 j = b0; j < end; ++j) cnt += (cand[j] > key) ? 1u : 0u;
        r = b0 + cnt;
    }
    if (r >= (u32)PRE_NMS) return;
    u32 flat = ~((u32)key);
    int p = (int)(flat >> 1);
    int cls = (int)(flat & 1u) + 1;
    int b = p / n_anch;
    int g = b * 3 + cls;
    int aidx = p - b * n_anch;
    float score = __uint_as_float(bits);
    float4 a = anchors4[aidx];
    float4 d = deltas4[p];
    float d0 = d.x * 0.1f, d1 = d.y * 0.1f, d2 = d.z * 0.2f, d3 = d.w * 0.2f;
    float y1 = a.x * (1.0f / 512.0f), x1 = a.y * (1.0f / 512.0f);
    float y2 = a.z * (1.0f / 512.0f), x2 = a.w * (1.0f / 512.0f);
    float h = y2 - y1, w = x2 - x1;
    float cy = y1 + 0.5f * h + d0 * h;
    float cx = x1 + 0.5f * w + d1 * w;
    h = h * expf(d2);
    w = w * expf(d3);
    float ry1 = (cy - 0.5f * h) * 512.0f;
    float rx1 = (cx - 0.5f * w) * 512.0f;
    float ry2 = (cy - 0.5f * h + h) * 512.0f;
    float rx2 = (cx - 0.5f * w + w) * 512.0f;
    ry1 = fminf(fmaxf(ry1, 0.0f), 512.0f);
    rx1 = fminf(fmaxf(rx1, 0.0f), 512.0f);
    ry2 = fminf(fmaxf(ry2, 0.0f), 512.0f);
    rx2 = fminf(fmaxf(rx2, 0.0f), 512.0f);
    out[r * 6 + 0] = ry1;
    out[r * 6 + 1] = rx1;
    out[r * 6 + 2] = ry2;
    out[r * 6 + 3] = rx2;
    out[r * 6 + 4] = score;
    out[r * 6 + 5] = 1.0f;               /* default keep; greedy overwrites */
    out[PRE_NMS * 6 + r] = (float)cls;
    out[PRE_NMS * 7 + r] = (float)b;
    boxr[r] = make_float4(ry1, rx1, ry2, rx2);
    atomicOr(&gbits[g * 192 + (r >> 5)], 1u << (r & 31));
}

/* 5: per-group prep + mask fused. Bitmap prefix -> rank-ordered boxes in LDS,
   then register-shuffle 64x64 IoU tiles (8 waves round-robin) -> maskg. */
__global__ __launch_bounds__(512) void prepmask_kernel(const u32* __restrict__ gbits,
                                                       const float4* __restrict__ boxr,
                                                       u32* __restrict__ kg,
                                                       u32* __restrict__ grankg,
                                                       u64* __restrict__ maskg) {
    __shared__ int bpre[96];
    __shared__ u16 grankS[KMAX];
    __shared__ float4 sbox[KMAX];
    __shared__ float sarea[KMAX];
    __shared__ int sK;
    int g = blockIdx.x, t = threadIdx.x, lane = t & 63, wv = t >> 6;
    const u32* rb32 = gbits + g * 192;

    if (t < 64) {
        u64 w0 = (u64)rb32[2 * lane] | ((u64)rb32[2 * lane + 1] << 32);
        u64 w1 = (lane < NBLK - 64)
                 ? ((u64)rb32[128 + 2 * lane] | ((u64)rb32[129 + 2 * lane] << 32)) : 0ull;
        int c0 = (int)__popcll(w0), c1 = (int)__popcll(w1);
        int i0 = c0, i1 = c1;
        #pragma unroll
        for (int off = 1; off < 64; off <<= 1) {
            int a = __shfl_up(i0, off); if (lane >= off) i0 += a;
            int b = __shfl_up(i1, off); if (lane >= off) i1 += b;
        }
        int tot0 = __shfl(i0, 63), tot1 = __shfl(i1, 63);
        bpre[lane] = i0 - c0;
        if (lane < 32) bpre[64 + lane] = tot0 + ((lane < NBLK - 64) ? (i1 - c1) : 0);
        if (lane == 0) { sK = tot0 + tot1; kg[g] = (u32)(tot0 + tot1); }
    }
    __syncthreads();
    int K = sK;
    if (K == 0) return;
    int Kc = (K < KMAX) ? K : KMAX;
    int W = (Kc + 63) >> 6;

    for (int blk = wv; blk < NBLK; blk += 8) {
        u64 wmask = (u64)rb32[2 * blk] | ((u64)rb32[2 * blk + 1] << 32);
        if ((wmask >> lane) & 1ull) {
            int pos = bpre[blk] + (int)__popcll(wmask & ((1ull << lane) - 1ull));
            if (pos < KMAX) grankS[pos] = (u16)((blk << 6) | lane);
        }
    }
    __syncthreads();

    for (int m = t; m < KMAX; m += 512) {
        if (m < Kc) {
            int r = grankS[m];
            float4 bb = boxr[r];
            sbox[m] = bb;
            sarea[m] = (bb.z - bb.x + 1.0f) * (bb.w - bb.y + 1.0f);
            grankg[g * KMAX + m] = (u32)r;
        } else {
            sbox[m] = make_float4(-3e30f, -3e30f, -3e30f, -3e30f);
            sarea[m] = 3e38f;
        }
    }
    __syncthreads();

    /* mask tiles: unit (c, rbk) round-robined over 8 waves */
    u64* mg = maskg + (size_t)g * (KMAX * MSTRIDE);
    for (int u = wv; u < W * W; u += 8) {
        int c = u / W, rbk = u % W;
        int r = rbk * 64 + lane;
        if (rbk > c) { mg[r * MSTRIDE + c] = 0ull; continue; }
        int j0 = c << 6;
        float4 rb = sbox[r];
        float  ra = sarea[r];
        float4 cb = sbox[j0 + lane];
        float  ca = sarea[j0 + lane];
        u64 word = 0ull;
        #pragma unroll 8
        for (int q = 0; q < 64; ++q) {
            float cbx = __shfl(cb.x, q);
            float cby = __shfl(cb.y, q);
            float cbz = __shfl(cb.z, q);
            float cbw = __shfl(cb.w, q);
            float cav = __shfl(ca, q);
            float ih = fminf(rb.z, cbz) - fmaxf(rb.x, cbx) + 1.0f;
            float iw = fminf(rb.w, cbw) - fmaxf(rb.y, cby) + 1.0f;
            ih = fmaxf(ih, 0.0f); iw = fmaxf(iw, 0.0f);
            /* iou>=0.5 <=> 3*inter >= ai+aj */
            bool o = (3.0f * ih * iw >= ra + cav) && ((j0 + q) > r);
            if (o) word |= (1ull << q);
        }
        mg[r * MSTRIDE + c] = word;
    }
}

/* 6: per-group serial greedy. Stage mask L2->LDS coalesced, then chunk-8 scan. */
__global__ __launch_bounds__(512) void greedy_kernel(const u32* __restrict__ kg,
                                                     const u32* __restrict__ grankg,
                                                     const u64* __restrict__ maskg,
                                                     float* __restrict__ out) {
    __shared__ u64 maskm[KMAX * MSTRIDE + 64];   /* 56.8 KB */
    __shared__ u16 grank[KMAX];
    int g = blockIdx.x, t = threadIdx.x, lane = t & 63;
    u32 K = kg[g];
    if (K == 0u) return;
    int Kc = (K < (u32)KMAX) ? (int)K : KMAX;
    int W = (Kc + 63) >> 6;
    const u64* mg = maskg + (size_t)g * (KMAX * MSTRIDE);
    int nw = Kc * MSTRIDE;
    for (int m = t; m < nw; m += 512) maskm[m] = mg[m];
    for (int m = nw + t; m < nw + 64; m += 512) maskm[m] = 0ull;
    for (int m = t; m < Kc; m += 512) grank[m] = (u16)grankg[g * KMAX + m];
    __syncthreads();

    if (t >= 64) return;
    u64 remv = 0ull;
    for (int w = 0; w < W; ++w) {
        int r0 = w << 6;
        int rend = Kc - r0; if (rend > 64) rend = 64;
        u64 curw = __shfl(remv, w);
        u64 kb = 0ull;
        for (int b0 = 0; b0 < rend; b0 += 8) {
            int n = rend - b0; if (n > 8) n = 8;
            u64 mrow[8], dg[8];
            #pragma unroll
            for (int j = 0; j < 8; ++j) {
                int rr = r0 + b0 + ((j < n) ? j : 0);
                mrow[j] = maskm[rr * MSTRIDE + lane];   /* +64 pad covers overrun */
                dg[j]   = maskm[rr * MSTRIDE + w];      /* uniform: broadcast */
            }
            #pragma unroll
            for (int j = 0; j < 8; ++j) {
                if (j < n) {
                    int b = b0 + j;
                    u64 km = ((curw >> b) & 1ull) ? 0ull : ~0ull;
                    curw |= dg[j] & km;
                    remv |= mrow[j] & km;
                    kb |= km & (1ull << b);
                }
            }
        }
        if (lane < rend)
            out[(int)grank[r0 + lane] * 6 + 5] = ((kb >> lane) & 1ull) ? 1.0f : 0.0f;
    }
}

extern "C" void kernel_launch(void* const* d_in, const int* in_sizes, int n_in,
                              void* d_out, int out_size, void* d_ws, size_t ws_size,
                              hipStream_t stream) {
    const float*  probs    = (const float*)d_in[0];
    const float4* deltas4  = (const float4*)d_in[1];
    const float4* anchors4 = (const float4*)d_in[2];
    int n_prop = in_sizes[1] / 4;   /* 522240 */
    int n_anch = in_sizes[2] / 4;   /* 65280  */

    char* ws = (char*)d_ws;
    u32* ctr      = (u32*)(ws + CTR_OFF);
    u64* cand     = (u64*)(ws + CAND_OFF);
    float4* boxr  = (float4*)(ws + BOXR_OFF);
    u32* gbits    = (u32*)(ws + GBITS_OFF);
    u32* kg       = (u32*)(ws + KG_OFF);
    u32* grankg   = (u32*)(ws + GRANKG_OFF);
    u64* maskg    = (u64*)(ws + MASKG_OFF);
    u32* base     = (u32*)(ws + BASE_OFF);
    u32* bcnt     = (u32*)(ws + BCNT_OFF);
    u32* partials = (u32*)(ws + PART_OFF);
    float* out    = (float*)d_out;

    hist_kernel<<<NHB, 1024, 0, stream>>>((const float4*)probs, partials, n_prop);
    pivot_kernel<<<1, 1024, 0, stream>>>(partials, ctr, base, bcnt, gbits);
    scatter_kernel<<<128, 256, 0, stream>>>((const float4*)probs, ctr, base, bcnt,
                                            cand, n_prop);
    rankdecode_kernel<<<CANDMAX / 256, 256, 0, stream>>>(cand, ctr, base, bcnt,
                                                         deltas4, anchors4,
                                                         boxr, gbits, out, n_anch);
    prepmask_kernel<<<NGRP, 512, 0, stream>>>(gbits, boxr, kg, grankg, maskg);
    greedy_kernel<<<NGRP, 512, 0, stream>>>(kg, grankg, maskg, out);
}

// Round 7
// 171.413 us; speedup vs baseline: 2.3957x; 1.2229x over previous
//
#include <hip/hip_runtime.h>
#include <math.h>

typedef unsigned int u32;
typedef unsigned short u16;
typedef unsigned long long u64;

#define PRE_NMS 6000
#define NBLK    94          /* ceil(6000/64) rank-bitmap words */
#define KMAX    640         /* group capacity (E[K]~375) */
#define MSTRIDE 11          /* mask row stride, > KMAX/64 */
#define MAXW    10          /* max 64-blocks per group */
#define MTILE   (MAXW * MAXW)
#define FINEB   8192        /* [0.5,1) buckets, 2^10 ulp each */
#define LOWB    8064        /* [0,0.5) buckets, bits>>17 */
#define TOTB    (FINEB + LOWB)
#define NHB     32          /* hist partial copies */
#define CANDMAX 16384
#define NGRP    24
#define FLOOR_BITS 0x3F000000u   /* 0.5f */

/* ws byte offsets */
#define CTR_OFF    0          /* 64 u32: [0]=M [1]=pivot bits */
#define CAND_OFF   256        /* 16384 u64 -> 131328 */
#define BOXR_OFF   131328     /* 6016 float4 -> 227584 */
#define GBITS_OFF  227584     /* 24*192 u32 -> 246016 */
#define KG_OFF     246016     /* 64 u32 -> 246272 */
#define GRANKG_OFF 246272     /* 24*640 u32 -> 307712 */
#define BOXG_OFF   307712     /* 24*640 float4 -> 553472 */
#define AREAG_OFF  553472     /* 24*640 f32 -> 614912 */
#define MASKG_OFF  614912     /* 24*640*11 u64 -> 1966592 */
#define BASE_OFF   1966592    /* 16384 u32 -> 2032128 */
#define BCNT_OFF   2032128    /* 16384 u32 -> 2097664 */
#define PART_OFF   2097664    /* 32 x 16256 u32 -> 4178432 */

/* bucket index in [0,16384): fine fb in [0,8192), low 8192+lb */
__device__ __forceinline__ u32 bucket_of(u32 bits) {
    if (bits >= FLOOR_BITS) {
        u32 fb = (bits - FLOOR_BITS) >> 10; if (fb > FINEB - 1) fb = FINEB - 1;
        return fb;
    }
    return 8192u + (bits >> 17);
}

/* 1: dual-range partial histograms (per-block copies) */
__global__ __launch_bounds__(1024) void hist_kernel(const float4* __restrict__ probs4,
                                                    u32* __restrict__ partials, int n_prop) {
    __shared__ u32 hf[FINEB];      /* 32 KB */
    __shared__ u32 hl[2][LOWB];    /* 63 KB */
    int t = threadIdx.x;
    for (int i = t; i < FINEB; i += 1024) hf[i] = 0u;
    for (int i = t; i < 2 * LOWB; i += 1024) ((u32*)hl)[i] = 0u;
    __syncthreads();
    u32* l = hl[(t >> 6) & 1];
    int nq = n_prop >> 2;
    int idx = blockIdx.x * 1024 + t;
    int stride = gridDim.x * 1024;
    for (int q = idx; q < nq; q += stride) {
        float4 a = probs4[3 * q + 0];
        float4 b = probs4[3 * q + 1];
        float4 c = probs4[3 * q + 2];
        float vs[8] = {a.y, a.z, b.x, b.y, b.w, c.x, c.z, c.w};
        #pragma unroll
        for (int e = 0; e < 8; ++e) {
            u32 bits = __float_as_uint(vs[e]);
            if (bits >= FLOOR_BITS) {
                u32 fb = (bits - FLOOR_BITS) >> 10; if (fb >= FINEB) fb = FINEB - 1;
                atomicAdd(&hf[fb], 1u);
            } else {
                atomicAdd(&l[bits >> 17], 1u);
            }
        }
    }
    __syncthreads();
    u32* outp = partials + blockIdx.x * TOTB;
    for (int b = t; b < FINEB; b += 1024) outp[b] = hf[b];
    for (int b = t; b < LOWB; b += 1024) outp[FINEB + b] = hl[0][b] + hl[1][b];
}

/* 2: reduce partials, suffix-scan from top -> exact pivot + per-bucket base
   ranks (# keys in strictly-higher buckets); zero ctr/bcnt/gbits. */
__global__ __launch_bounds__(1024) void pivot_kernel(const u32* __restrict__ partials,
                                                     u32* __restrict__ ctr,
                                                     u32* __restrict__ base,
                                                     u32* __restrict__ bcnt,
                                                     u32* __restrict__ gbits) {
    __shared__ u32 fh[FINEB];
    __shared__ u32 sd[1024];
    int t = threadIdx.x;
    for (int i = t; i < 16384; i += 1024) bcnt[i] = 0u;
    for (int i = t; i < NGRP * 192; i += 1024) gbits[i] = 0u;
    if (t == 0) { ctr[0] = 0u; ctr[1] = 0u; }
    for (int b = t; b < FINEB; b += 1024) {
        u32 s = 0;
        #pragma unroll
        for (int k = 0; k < NHB; ++k) s += partials[k * TOTB + b];
        fh[b] = s;
    }
    __syncthreads();
    int hi = FINEB - 1 - 8 * t;
    u32 L = 0;
    #pragma unroll
    for (int e = 0; e < 8; ++e) L += fh[hi - e];
    sd[t] = L;
    __syncthreads();
    for (int off = 1; off < 1024; off <<= 1) {
        u32 x = (t >= off) ? sd[t - off] : 0u;
        __syncthreads();
        sd[t] += x;
        __syncthreads();
    }
    u32 incl = sd[t], excl = incl - L;
    u32 fineTotal = sd[1023];
    {
        u32 run = excl;
        #pragma unroll
        for (int e = 0; e < 8; ++e) {
            int fb = hi - e;
            base[fb] = run;
            u32 c = fh[fb];
            if (run < (u32)PRE_NMS && run + c >= (u32)PRE_NMS) {
                ctr[1] = FLOOR_BITS + ((u32)fb << 10);
                u32 m = run + c; if (m > (u32)CANDMAX) m = (u32)CANDMAX;
                ctr[0] = m;
            }
            run += c;
        }
    }
    if (fineTotal >= (u32)PRE_NMS) return;

    /* fallback (never expected): continue into [0, 0.5) coarse buckets */
    u32 rem = (u32)PRE_NMS - fineTotal;
    __syncthreads();
    for (int b = t; b < FINEB; b += 1024) {
        u32 s = 0;
        if (b < LOWB) {
            #pragma unroll
            for (int k = 0; k < NHB; ++k) s += partials[k * TOTB + FINEB + b];
        }
        fh[b] = s;
    }
    __syncthreads();
    L = 0;
    #pragma unroll
    for (int e = 0; e < 8; ++e) L += fh[hi - e];
    sd[t] = L;
    __syncthreads();
    for (int off = 1; off < 1024; off <<= 1) {
        u32 x = (t >= off) ? sd[t - off] : 0u;
        __syncthreads();
        sd[t] += x;
        __syncthreads();
    }
    incl = sd[t]; excl = incl - L;
    {
        u32 run = excl;
        #pragma unroll
        for (int e = 0; e < 8; ++e) {
            int lb = hi - e;
            base[8192 + lb] = fineTotal + run;
            u32 c = fh[lb];
            if (run < rem && run + c >= rem) {
                ctr[1] = ((u32)lb) << 17;
                u32 m = fineTotal + run + c; if (m > (u32)CANDMAX) m = (u32)CANDMAX;
                ctr[0] = m;
            }
            run += c;
        }
    }
}

/* 3: scatter-compact: candidate -> its bucket's contiguous slot range. */
__global__ __launch_bounds__(256) void scatter_kernel(const float4* __restrict__ probs4,
                                                      const u32* __restrict__ ctr,
                                                      const u32* __restrict__ base,
                                                      u32* __restrict__ bcnt,
                                                      u64* __restrict__ cand,
                                                      int n_prop) {
    u32 pivot = ctr[1];
    int nq = n_prop >> 2;
    int idx = blockIdx.x * 256 + threadIdx.x;
    int stride = gridDim.x * 256;
    for (int q = idx; q < nq; q += stride) {
        float4 a = probs4[3 * q + 0];
        float4 b = probs4[3 * q + 1];
        float4 c = probs4[3 * q + 2];
        float vs[8] = {a.y, a.z, b.x, b.y, b.w, c.x, c.z, c.w};
        #pragma unroll
        for (int e = 0; e < 8; ++e) {
            u32 bits = __float_as_uint(vs[e]);
            if (bits >= pivot) {
                u32 bk = bucket_of(bits);
                u32 off = atomicAdd(&bcnt[bk], 1u);
                u32 slot = base[bk] + off;
                u32 i = (u32)(8 * q + e);
                if (slot < (u32)CANDMAX) cand[slot] = ((u64)bits << 32) | (u64)(~i);
            }
        }
    }
}

/* 4: local rank (bucket base + count-greater among tiny bucket group) + decode. */
__global__ __launch_bounds__(256) void rankdecode_kernel(const u64* __restrict__ cand,
                                                         const u32* __restrict__ ctr,
                                                         const u32* __restrict__ base,
                                                         const u32* __restrict__ bcnt,
                                                         const float4* __restrict__ deltas4,
                                                         const float4* __restrict__ anchors4,
                                                         float4* __restrict__ boxr,
                                                         u32* __restrict__ gbits,
                                                         float* __restrict__ out,
                                                         int n_anch) {
    u32 M = ctr[0]; if (M > (u32)CANDMAX) M = (u32)CANDMAX;
    u32 i = blockIdx.x * 256 + threadIdx.x;
    if (i >= M) return;
    u64 key = cand[i];
    u32 bits = (u32)(key >> 32);
    u32 bk = bucket_of(bits);
    u32 b0 = base[bk];
    u32 n = bcnt[bk];
    u32 r = b0;
    if (n > 1) {
        u32 end = b0 + n; if (end > M) end = M;
        u32 cnt = 0;
        for (u32 j = b0; j < end; ++j) cnt += (cand[j] > key) ? 1u : 0u;
        r = b0 + cnt;
    }
    if (r >= (u32)PRE_NMS) return;
    u32 flat = ~((u32)key);
    int p = (int)(flat >> 1);
    int cls = (int)(flat & 1u) + 1;
    int b = p / n_anch;
    int g = b * 3 + cls;
    int aidx = p - b * n_anch;
    float score = __uint_as_float(bits);
    float4 a = anchors4[aidx];
    float4 d = deltas4[p];
    float d0 = d.x * 0.1f, d1 = d.y * 0.1f, d2 = d.z * 0.2f, d3 = d.w * 0.2f;
    float y1 = a.x * (1.0f / 512.0f), x1 = a.y * (1.0f / 512.0f);
    float y2 = a.z * (1.0f / 512.0f), x2 = a.w * (1.0f / 512.0f);
    float h = y2 - y1, w = x2 - x1;
    float cy = y1 + 0.5f * h + d0 * h;
    float cx = x1 + 0.5f * w + d1 * w;
    h = h * expf(d2);
    w = w * expf(d3);
    float ry1 = (cy - 0.5f * h) * 512.0f;
    float rx1 = (cx - 0.5f * w) * 512.0f;
    float ry2 = (cy - 0.5f * h + h) * 512.0f;
    float rx2 = (cx - 0.5f * w + w) * 512.0f;
    ry1 = fminf(fmaxf(ry1, 0.0f), 512.0f);
    rx1 = fminf(fmaxf(rx1, 0.0f), 512.0f);
    ry2 = fminf(fmaxf(ry2, 0.0f), 512.0f);
    rx2 = fminf(fmaxf(rx2, 0.0f), 512.0f);
    out[r * 6 + 0] = ry1;
    out[r * 6 + 1] = rx1;
    out[r * 6 + 2] = ry2;
    out[r * 6 + 3] = rx2;
    out[r * 6 + 4] = score;
    out[r * 6 + 5] = 1.0f;               /* default keep; greedy overwrites */
    out[PRE_NMS * 6 + r] = (float)cls;
    out[PRE_NMS * 7 + r] = (float)b;
    boxr[r] = make_float4(ry1, rx1, ry2, rx2);
    atomicOr(&gbits[g * 192 + (r >> 5)], 1u << (r & 31));
}

/* 5: per-group prep: bitmap prefix -> rank-ordered box table in global
   (sentinel-padded to KMAX), grank table, K. */
__global__ __launch_bounds__(512) void prep_kernel(const u32* __restrict__ gbits,
                                                   const float4* __restrict__ boxr,
                                                   u32* __restrict__ kg,
                                                   u32* __restrict__ grankg,
                                                   float4* __restrict__ boxg,
                                                   float* __restrict__ areag) {
    __shared__ int bpre[96];
    __shared__ u16 grankS[KMAX];
    __shared__ int sK;
    int g = blockIdx.x, t = threadIdx.x, lane = t & 63, wv = t >> 6;
    const u32* rb32 = gbits + g * 192;

    if (t < 64) {
        u64 w0 = (u64)rb32[2 * lane] | ((u64)rb32[2 * lane + 1] << 32);
        u64 w1 = (lane < NBLK - 64)
                 ? ((u64)rb32[128 + 2 * lane] | ((u64)rb32[129 + 2 * lane] << 32)) : 0ull;
        int c0 = (int)__popcll(w0), c1 = (int)__popcll(w1);
        int i0 = c0, i1 = c1;
        #pragma unroll
        for (int off = 1; off < 64; off <<= 1) {
            int a = __shfl_up(i0, off); if (lane >= off) i0 += a;
            int b = __shfl_up(i1, off); if (lane >= off) i1 += b;
        }
        int tot0 = __shfl(i0, 63), tot1 = __shfl(i1, 63);
        bpre[lane] = i0 - c0;
        if (lane < 32) bpre[64 + lane] = tot0 + ((lane < NBLK - 64) ? (i1 - c1) : 0);
        if (lane == 0) { sK = tot0 + tot1; kg[g] = (u32)(tot0 + tot1); }
    }
    __syncthreads();
    int K = sK;
    if (K == 0) return;
    int Kc = (K < KMAX) ? K : KMAX;

    for (int blk = wv; blk < NBLK; blk += 8) {
        u64 wmask = (u64)rb32[2 * blk] | ((u64)rb32[2 * blk + 1] << 32);
        if ((wmask >> lane) & 1ull) {
            int pos = bpre[blk] + (int)__popcll(wmask & ((1ull << lane) - 1ull));
            if (pos < KMAX) grankS[pos] = (u16)((blk << 6) | lane);
        }
    }
    __syncthreads();

    float4* bg = boxg + g * KMAX;
    float*  ag = areag + g * KMAX;
    u32*    gr = grankg + g * KMAX;
    for (int m = t; m < KMAX; m += 512) {
        if (m < Kc) {
            int r = grankS[m];
            float4 bb = boxr[r];
            bg[m] = bb;
            ag[m] = (bb.z - bb.x + 1.0f) * (bb.w - bb.y + 1.0f);
            gr[m] = (u32)r;
        } else {
            bg[m] = make_float4(-3e30f, -3e30f, -3e30f, -3e30f);
            ag[m] = 3e38f;
        }
    }
}

/* 6: register-resident 64x64 IoU tiles, one 1-wave block per (group, tile).
   Lane holds its row box AND its column box; column broadcast via shuffle.
   Sub-diagonal tiles write zeros. Spread across the whole machine. */
__global__ __launch_bounds__(64) void mask_kernel(const u32* __restrict__ kg,
                                                  const float4* __restrict__ boxg,
                                                  const float* __restrict__ areag,
                                                  u64* __restrict__ maskg) {
    int g = blockIdx.y;
    u32 K = kg[g];
    if (K == 0u) return;
    int Kc = (K < (u32)KMAX) ? (int)K : KMAX;
    int W = (Kc + 63) >> 6;
    int u = blockIdx.x;
    int c = u / MAXW, rbk = u % MAXW;
    if (c >= W || rbk >= W) return;
    int lane = threadIdx.x;
    int r = rbk * 64 + lane;
    u64* mg = maskg + (size_t)g * (KMAX * MSTRIDE);
    if (rbk > c) { mg[r * MSTRIDE + c] = 0ull; return; }
    int j0 = c << 6;
    const float4* bg = boxg + g * KMAX;
    const float*  ag = areag + g * KMAX;
    float4 rb = bg[r];
    float  ra = ag[r];
    float4 cb = bg[j0 + lane];
    float  ca = ag[j0 + lane];
    u64 word = 0ull;
    #pragma unroll 8
    for (int q = 0; q < 64; ++q) {
        float cbx = __shfl(cb.x, q);
        float cby = __shfl(cb.y, q);
        float cbz = __shfl(cb.z, q);
        float cbw = __shfl(cb.w, q);
        float cav = __shfl(ca, q);
        float ih = fminf(rb.z, cbz) - fmaxf(rb.x, cbx) + 1.0f;
        float iw = fminf(rb.w, cbw) - fmaxf(rb.y, cby) + 1.0f;
        ih = fmaxf(ih, 0.0f); iw = fmaxf(iw, 0.0f);
        /* iou>=0.5 <=> 3*inter >= ai+aj */
        bool o = (3.0f * ih * iw >= ra + cav) && ((j0 + q) > r);
        if (o) word |= (1ull << q);
    }
    mg[r * MSTRIDE + c] = word;
}

/* 7: per-group serial greedy. Stage mask L2->LDS coalesced, then chunk-8 scan. */
__global__ __launch_bounds__(512) void greedy_kernel(const u32* __restrict__ kg,
                                                     const u32* __restrict__ grankg,
                                                     const u64* __restrict__ maskg,
                                                     float* __restrict__ out) {
    __shared__ u64 maskm[KMAX * MSTRIDE + 64];   /* 56.8 KB */
    __shared__ u16 grank[KMAX];
    int g = blockIdx.x, t = threadIdx.x, lane = t & 63;
    u32 K = kg[g];
    if (K == 0u) return;
    int Kc = (K < (u32)KMAX) ? (int)K : KMAX;
    int W = (Kc + 63) >> 6;
    const u64* mg = maskg + (size_t)g * (KMAX * MSTRIDE);
    int nw = Kc * MSTRIDE;
    for (int m = t; m < nw; m += 512) maskm[m] = mg[m];
    for (int m = nw + t; m < nw + 64; m += 512) maskm[m] = 0ull;
    for (int m = t; m < Kc; m += 512) grank[m] = (u16)grankg[g * KMAX + m];
    __syncthreads();

    if (t >= 64) return;
    u64 remv = 0ull;
    for (int w = 0; w < W; ++w) {
        int r0 = w << 6;
        int rend = Kc - r0; if (rend > 64) rend = 64;
        u64 curw = __shfl(remv, w);
        u64 kb = 0ull;
        for (int b0 = 0; b0 < rend; b0 += 8) {
            int n = rend - b0; if (n > 8) n = 8;
            u64 mrow[8], dg[8];
            #pragma unroll
            for (int j = 0; j < 8; ++j) {
                int rr = r0 + b0 + ((j < n) ? j : 0);
                mrow[j] = maskm[rr * MSTRIDE + lane];   /* +64 pad covers overrun */
                dg[j]   = maskm[rr * MSTRIDE + w];      /* uniform: broadcast */
            }
            #pragma unroll
            for (int j = 0; j < 8; ++j) {
                if (j < n) {
                    int b = b0 + j;
                    u64 km = ((curw >> b) & 1ull) ? 0ull : ~0ull;
                    curw |= dg[j] & km;
                    remv |= mrow[j] & km;
                    kb |= km & (1ull << b);
                }
            }
        }
        if (lane < rend)
            out[(int)grank[r0 + lane] * 6 + 5] = ((kb >> lane) & 1ull) ? 1.0f : 0.0f;
    }
}

extern "C" void kernel_launch(void* const* d_in, const int* in_sizes, int n_in,
                              void* d_out, int out_size, void* d_ws, size_t ws_size,
                              hipStream_t stream) {
    const float*  probs    = (const float*)d_in[0];
    const float4* deltas4  = (const float4*)d_in[1];
    const float4* anchors4 = (const float4*)d_in[2];
    int n_prop = in_sizes[1] / 4;   /* 522240 */
    int n_anch = in_sizes[2] / 4;   /* 65280  */

    char* ws = (char*)d_ws;
    u32* ctr      = (u32*)(ws + CTR_OFF);
    u64* cand     = (u64*)(ws + CAND_OFF);
    float4* boxr  = (float4*)(ws + BOXR_OFF);
    u32* gbits    = (u32*)(ws + GBITS_OFF);
    u32* kg       = (u32*)(ws + KG_OFF);
    u32* grankg   = (u32*)(ws + GRANKG_OFF);
    float4* boxg  = (float4*)(ws + BOXG_OFF);
    float* areag  = (float*)(ws + AREAG_OFF);
    u64* maskg    = (u64*)(ws + MASKG_OFF);
    u32* base     = (u32*)(ws + BASE_OFF);
    u32* bcnt     = (u32*)(ws + BCNT_OFF);
    u32* partials = (u32*)(ws + PART_OFF);
    float* out    = (float*)d_out;

    hist_kernel<<<NHB, 1024, 0, stream>>>((const float4*)probs, partials, n_prop);
    pivot_kernel<<<1, 1024, 0, stream>>>(partials, ctr, base, bcnt, gbits);
    scatter_kernel<<<256, 256, 0, stream>>>((const float4*)probs, ctr, base, bcnt,
                                            cand, n_prop);
    rankdecode_kernel<<<CANDMAX / 256, 256, 0, stream>>>(cand, ctr, base, bcnt,
                                                         deltas4, anchors4,
                                                         boxr, gbits, out, n_anch);
    prep_kernel<<<NGRP, 512, 0, stream>>>(gbits, boxr, kg, grankg, boxg, areag);
    mask_kernel<<<dim3(MTILE, NGRP), 64, 0, stream>>>(kg, boxg, areag, maskg);
    greedy_kernel<<<NGRP, 512, 0, stream>>>(kg, grankg, maskg, out);
}

// Round 8
// 140.069 us; speedup vs baseline: 2.9318x; 1.2238x over previous
//
#include <hip/hip_runtime.h>
#include <math.h>

typedef unsigned int u32;
typedef unsigned short u16;
typedef unsigned long long u64;

#define PRE_NMS 6000
#define NBLK    94          /* ceil(6000/64) rank-bitmap words */
#define KMAX    640         /* group capacity (E[K]~375) */
#define MSTRIDE 11          /* mask row stride, > KMAX/64 */
#define MAXW    10          /* max 64-blocks per group */
#define MTILE   (MAXW * MAXW)
#define FINEB   8192        /* [0.5,1) buckets, 2^10 ulp each */
#define LOWB    8064        /* [0,0.5) buckets, bits>>17 */
#define NHB     64          /* hist blocks / low-partial copies */
#define CANDMAX 16384
#define NGRP    24
#define FLOOR_BITS 0x3F000000u   /* 0.5f */

/* ws byte offsets (FINEH|BCNT|GBITS contiguous -> one memset) */
#define CTR_OFF    0          /* 64 u32 -> 256 */
#define FINEH_OFF  256        /* 8192 u32 -> 33024 */
#define BCNT_OFF   33024      /* 16384 u32 -> 98560 */
#define GBITS_OFF  98560      /* 24*192 u32 -> 116992 */
#define ZERO_LEN   (32768 + 65536 + 18432)   /* 116736 bytes from FINEH_OFF */
#define CAND_OFF   116992     /* 16384 u64 -> 248064 */
#define BOXR_OFF   248064     /* 6016 float4 -> 344320 */
#define KG_OFF     344320     /* 64 u32 -> 344576 */
#define GRANKG_OFF 344576     /* 24*640 u32 -> 406016 */
#define BOXG_OFF   406016     /* 24*640 float4 -> 651776 */
#define AREAG_OFF  651776     /* 24*640 f32 -> 713216 */
#define MASKG_OFF  713216     /* 24*640*11 u64 -> 2064896 */
#define BASE_OFF   2064896    /* 16384 u32 -> 2130432 */
#define PART_OFF   2130432    /* 64 x 8064 u32 (low-range only) -> 4194816 */

/* bucket index in [0,16384): fine fb in [0,8192), low 8192+lb */
__device__ __forceinline__ u32 bucket_of(u32 bits) {
    if (bits >= FLOOR_BITS) {
        u32 fb = (bits - FLOOR_BITS) >> 10; if (fb > FINEB - 1) fb = FINEB - 1;
        return fb;
    }
    return 8192u + (bits >> 17);
}

/* 1: histogram. Fine range merged straight into global fineh (sparse atomics,
   pre-zeroed by memset); low range kept as per-block partials (fallback only). */
__global__ __launch_bounds__(1024) void hist_kernel(const float4* __restrict__ probs4,
                                                    u32* __restrict__ fineh,
                                                    u32* __restrict__ partials, int n_prop) {
    __shared__ u32 hf[FINEB];      /* 32 KB */
    __shared__ u32 hl[2][LOWB];    /* 63 KB */
    int t = threadIdx.x;
    for (int i = t; i < FINEB; i += 1024) hf[i] = 0u;
    for (int i = t; i < 2 * LOWB; i += 1024) ((u32*)hl)[i] = 0u;
    __syncthreads();
    u32* l = hl[(t >> 6) & 1];
    int nq = n_prop >> 2;
    int idx = blockIdx.x * 1024 + t;
    int stride = gridDim.x * 1024;
    for (int q = idx; q < nq; q += stride) {
        float4 a = probs4[3 * q + 0];
        float4 b = probs4[3 * q + 1];
        float4 c = probs4[3 * q + 2];
        float vs[8] = {a.y, a.z, b.x, b.y, b.w, c.x, c.z, c.w};
        #pragma unroll
        for (int e = 0; e < 8; ++e) {
            u32 bits = __float_as_uint(vs[e]);
            if (bits >= FLOOR_BITS) {
                u32 fb = (bits - FLOOR_BITS) >> 10; if (fb >= FINEB) fb = FINEB - 1;
                atomicAdd(&hf[fb], 1u);
            } else {
                atomicAdd(&l[bits >> 17], 1u);
            }
        }
    }
    __syncthreads();
    for (int b = t; b < FINEB; b += 1024) {
        u32 v = hf[b];
        if (v) atomicAdd(&fineh[b], v);
    }
    u32* outp = partials + blockIdx.x * LOWB;
    for (int b = t; b < LOWB; b += 1024) outp[b] = hl[0][b] + hl[1][b];
}

/* 2: read pre-reduced fine histogram (32 KB), suffix-scan from top ->
   exact pivot + per-bucket base ranks. bcnt/gbits already zeroed by memset. */
__global__ __launch_bounds__(1024) void pivot_kernel(const u32* __restrict__ fineh,
                                                     const u32* __restrict__ partials,
                                                     u32* __restrict__ ctr,
                                                     u32* __restrict__ base) {
    __shared__ u32 fh[FINEB];
    __shared__ u32 sd[1024];
    int t = threadIdx.x;
    if (t == 0) { ctr[0] = 0u; ctr[1] = 0u; }
    for (int b = t; b < FINEB; b += 1024) fh[b] = fineh[b];
    __syncthreads();
    int hi = FINEB - 1 - 8 * t;
    u32 L = 0;
    #pragma unroll
    for (int e = 0; e < 8; ++e) L += fh[hi - e];
    sd[t] = L;
    __syncthreads();
    for (int off = 1; off < 1024; off <<= 1) {
        u32 x = (t >= off) ? sd[t - off] : 0u;
        __syncthreads();
        sd[t] += x;
        __syncthreads();
    }
    u32 incl = sd[t], excl = incl - L;
    u32 fineTotal = sd[1023];
    {
        u32 run = excl;
        #pragma unroll
        for (int e = 0; e < 8; ++e) {
            int fb = hi - e;
            base[fb] = run;
            u32 c = fh[fb];
            if (run < (u32)PRE_NMS && run + c >= (u32)PRE_NMS) {
                ctr[1] = FLOOR_BITS + ((u32)fb << 10);
                u32 m = run + c; if (m > (u32)CANDMAX) m = (u32)CANDMAX;
                ctr[0] = m;
            }
            run += c;
        }
    }
    if (fineTotal >= (u32)PRE_NMS) return;

    /* fallback (never expected): reduce low partials, continue scan */
    u32 rem = (u32)PRE_NMS - fineTotal;
    __syncthreads();
    for (int b = t; b < FINEB; b += 1024) {
        u32 s = 0;
        if (b < LOWB) {
            for (int k = 0; k < NHB; ++k) s += partials[k * LOWB + b];
        }
        fh[b] = s;
    }
    __syncthreads();
    L = 0;
    #pragma unroll
    for (int e = 0; e < 8; ++e) L += fh[hi - e];
    sd[t] = L;
    __syncthreads();
    for (int off = 1; off < 1024; off <<= 1) {
        u32 x = (t >= off) ? sd[t - off] : 0u;
        __syncthreads();
        sd[t] += x;
        __syncthreads();
    }
    incl = sd[t]; excl = incl - L;
    {
        u32 run = excl;
        #pragma unroll
        for (int e = 0; e < 8; ++e) {
            int lb = hi - e;
            base[8192 + lb] = fineTotal + run;
            u32 c = fh[lb];
            if (run < rem && run + c >= rem) {
                ctr[1] = ((u32)lb) << 17;
                u32 m = fineTotal + run + c; if (m > (u32)CANDMAX) m = (u32)CANDMAX;
                ctr[0] = m;
            }
            run += c;
        }
    }
}

/* 3: scatter-compact: candidate -> its bucket's contiguous slot range. */
__global__ __launch_bounds__(256) void scatter_kernel(const float4* __restrict__ probs4,
                                                      const u32* __restrict__ ctr,
                                                      const u32* __restrict__ base,
                                                      u32* __restrict__ bcnt,
                                                      u64* __restrict__ cand,
                                                      int n_prop) {
    u32 pivot = ctr[1];
    int nq = n_prop >> 2;
    int idx = blockIdx.x * 256 + threadIdx.x;
    int stride = gridDim.x * 256;
    for (int q = idx; q < nq; q += stride) {
        float4 a = probs4[3 * q + 0];
        float4 b = probs4[3 * q + 1];
        float4 c = probs4[3 * q + 2];
        float vs[8] = {a.y, a.z, b.x, b.y, b.w, c.x, c.z, c.w};
        #pragma unroll
        for (int e = 0; e < 8; ++e) {
            u32 bits = __float_as_uint(vs[e]);
            if (bits >= pivot) {
                u32 bk = bucket_of(bits);
                u32 off = atomicAdd(&bcnt[bk], 1u);
                u32 slot = base[bk] + off;
                u32 i = (u32)(8 * q + e);
                if (slot < (u32)CANDMAX) cand[slot] = ((u64)bits << 32) | (u64)(~i);
            }
        }
    }
}

/* 4: local rank (bucket base + count-greater among tiny bucket group) + decode. */
__global__ __launch_bounds__(256) void rankdecode_kernel(const u64* __restrict__ cand,
                                                         const u32* __restrict__ ctr,
                                                         const u32* __restrict__ base,
                                                         const u32* __restrict__ bcnt,
                                                         const float4* __restrict__ deltas4,
                                                         const float4* __restrict__ anchors4,
                                                         float4* __restrict__ boxr,
                                                         u32* __restrict__ gbits,
                                                         float* __restrict__ out,
                                                         int n_anch) {
    u32 M = ctr[0]; if (M > (u32)CANDMAX) M = (u32)CANDMAX;
    u32 i = blockIdx.x * 256 + threadIdx.x;
    if (i >= M) return;
    u64 key = cand[i];
    u32 bits = (u32)(key >> 32);
    u32 bk = bucket_of(bits);
    u32 b0 = base[bk];
    u32 n = bcnt[bk];
    u32 r = b0;
    if (n > 1) {
        u32 end = b0 + n; if (end > M) end = M;
        u32 cnt = 0;
        for (u32 j = b0; j < end; ++j) cnt += (cand[j] > key) ? 1u : 0u;
        r = b0 + cnt;
    }
    if (r >= (u32)PRE_NMS) return;
    u32 flat = ~((u32)key);
    int p = (int)(flat >> 1);
    int cls = (int)(flat & 1u) + 1;
    int b = p / n_anch;
    int g = b * 3 + cls;
    int aidx = p - b * n_anch;
    float score = __uint_as_float(bits);
    float4 a = anchors4[aidx];
    float4 d = deltas4[p];
    float d0 = d.x * 0.1f, d1 = d.y * 0.1f, d2 = d.z * 0.2f, d3 = d.w * 0.2f;
    float y1 = a.x * (1.0f / 512.0f), x1 = a.y * (1.0f / 512.0f);
    float y2 = a.z * (1.0f / 512.0f), x2 = a.w * (1.0f / 512.0f);
    float h = y2 - y1, w = x2 - x1;
    float cy = y1 + 0.5f * h + d0 * h;
    float cx = x1 + 0.5f * w + d1 * w;
    h = h * expf(d2);
    w = w * expf(d3);
    float ry1 = (cy - 0.5f * h) * 512.0f;
    float rx1 = (cx - 0.5f * w) * 512.0f;
    float ry2 = (cy - 0.5f * h + h) * 512.0f;
    float rx2 = (cx - 0.5f * w + w) * 512.0f;
    ry1 = fminf(fmaxf(ry1, 0.0f), 512.0f);
    rx1 = fminf(fmaxf(rx1, 0.0f), 512.0f);
    ry2 = fminf(fmaxf(ry2, 0.0f), 512.0f);
    rx2 = fminf(fmaxf(rx2, 0.0f), 512.0f);
    out[r * 6 + 0] = ry1;
    out[r * 6 + 1] = rx1;
    out[r * 6 + 2] = ry2;
    out[r * 6 + 3] = rx2;
    out[r * 6 + 4] = score;
    out[r * 6 + 5] = 1.0f;               /* default keep; greedy overwrites */
    out[PRE_NMS * 6 + r] = (float)cls;
    out[PRE_NMS * 7 + r] = (float)b;
    boxr[r] = make_float4(ry1, rx1, ry2, rx2);
    atomicOr(&gbits[g * 192 + (r >> 5)], 1u << (r & 31));
}

/* 5: per-group prep: bitmap prefix -> rank-ordered box table in global
   (sentinel-padded to KMAX), grank table, K. */
__global__ __launch_bounds__(512) void prep_kernel(const u32* __restrict__ gbits,
                                                   const float4* __restrict__ boxr,
                                                   u32* __restrict__ kg,
                                                   u32* __restrict__ grankg,
                                                   float4* __restrict__ boxg,
                                                   float* __restrict__ areag) {
    __shared__ int bpre[96];
    __shared__ u16 grankS[KMAX];
    __shared__ int sK;
    int g = blockIdx.x, t = threadIdx.x, lane = t & 63, wv = t >> 6;
    const u32* rb32 = gbits + g * 192;

    if (t < 64) {
        u64 w0 = (u64)rb32[2 * lane] | ((u64)rb32[2 * lane + 1] << 32);
        u64 w1 = (lane < NBLK - 64)
                 ? ((u64)rb32[128 + 2 * lane] | ((u64)rb32[129 + 2 * lane] << 32)) : 0ull;
        int c0 = (int)__popcll(w0), c1 = (int)__popcll(w1);
        int i0 = c0, i1 = c1;
        #pragma unroll
        for (int off = 1; off < 64; off <<= 1) {
            int a = __shfl_up(i0, off); if (lane >= off) i0 += a;
            int b = __shfl_up(i1, off); if (lane >= off) i1 += b;
        }
        int tot0 = __shfl(i0, 63), tot1 = __shfl(i1, 63);
        bpre[lane] = i0 - c0;
        if (lane < 32) bpre[64 + lane] = tot0 + ((lane < NBLK - 64) ? (i1 - c1) : 0);
        if (lane == 0) { sK = tot0 + tot1; kg[g] = (u32)(tot0 + tot1); }
    }
    __syncthreads();
    int K = sK;
    if (K == 0) return;
    int Kc = (K < KMAX) ? K : KMAX;

    for (int blk = wv; blk < NBLK; blk += 8) {
        u64 wmask = (u64)rb32[2 * blk] | ((u64)rb32[2 * blk + 1] << 32);
        if ((wmask >> lane) & 1ull) {
            int pos = bpre[blk] + (int)__popcll(wmask & ((1ull << lane) - 1ull));
            if (pos < KMAX) grankS[pos] = (u16)((blk << 6) | lane);
        }
    }
    __syncthreads();

    float4* bg = boxg + g * KMAX;
    float*  ag = areag + g * KMAX;
    u32*    gr = grankg + g * KMAX;
    for (int m = t; m < KMAX; m += 512) {
        if (m < Kc) {
            int r = grankS[m];
            float4 bb = boxr[r];
            bg[m] = bb;
            ag[m] = (bb.z - bb.x + 1.0f) * (bb.w - bb.y + 1.0f);
            gr[m] = (u32)r;
        } else {
            bg[m] = make_float4(-3e30f, -3e30f, -3e30f, -3e30f);
            ag[m] = 3e38f;
        }
    }
}

/* 6: register-resident 64x64 IoU tiles, one 1-wave block per (group, tile). */
__global__ __launch_bounds__(64) void mask_kernel(const u32* __restrict__ kg,
                                                  const float4* __restrict__ boxg,
                                                  const float* __restrict__ areag,
                                                  u64* __restrict__ maskg) {
    int g = blockIdx.y;
    u32 K = kg[g];
    if (K == 0u) return;
    int Kc = (K < (u32)KMAX) ? (int)K : KMAX;
    int W = (Kc + 63) >> 6;
    int u = blockIdx.x;
    int c = u / MAXW, rbk = u % MAXW;
    if (c >= W || rbk >= W) return;
    int lane = threadIdx.x;
    int r = rbk * 64 + lane;
    u64* mg = maskg + (size_t)g * (KMAX * MSTRIDE);
    if (rbk > c) { mg[r * MSTRIDE + c] = 0ull; return; }
    int j0 = c << 6;
    const float4* bg = boxg + g * KMAX;
    const float*  ag = areag + g * KMAX;
    float4 rb = bg[r];
    float  ra = ag[r];
    float4 cb = bg[j0 + lane];
    float  ca = ag[j0 + lane];
    u64 word = 0ull;
    #pragma unroll 8
    for (int q = 0; q < 64; ++q) {
        float cbx = __shfl(cb.x, q);
        float cby = __shfl(cb.y, q);
        float cbz = __shfl(cb.z, q);
        float cbw = __shfl(cb.w, q);
        float cav = __shfl(ca, q);
        float ih = fminf(rb.z, cbz) - fmaxf(rb.x, cbx) + 1.0f;
        float iw = fminf(rb.w, cbw) - fmaxf(rb.y, cby) + 1.0f;
        ih = fmaxf(ih, 0.0f); iw = fmaxf(iw, 0.0f);
        /* iou>=0.5 <=> 3*inter >= ai+aj */
        bool o = (3.0f * ih * iw >= ra + cav) && ((j0 + q) > r);
        if (o) word |= (1ull << q);
    }
    mg[r * MSTRIDE + c] = word;
}

/* 7: per-group serial greedy. Stage mask L2->LDS coalesced, then chunk-8 scan. */
__global__ __launch_bounds__(512) void greedy_kernel(const u32* __restrict__ kg,
                                                     const u32* __restrict__ grankg,
                                                     const u64* __restrict__ maskg,
                                                     float* __restrict__ out) {
    __shared__ u64 maskm[KMAX * MSTRIDE + 64];   /* 56.8 KB */
    __shared__ u16 grank[KMAX];
    int g = blockIdx.x, t = threadIdx.x, lane = t & 63;
    u32 K = kg[g];
    if (K == 0u) return;
    int Kc = (K < (u32)KMAX) ? (int)K : KMAX;
    int W = (Kc + 63) >> 6;
    const u64* mg = maskg + (size_t)g * (KMAX * MSTRIDE);
    int nw = Kc * MSTRIDE;
    for (int m = t; m < nw; m += 512) maskm[m] = mg[m];
    for (int m = nw + t; m < nw + 64; m += 512) maskm[m] = 0ull;
    for (int m = t; m < Kc; m += 512) grank[m] = (u16)grankg[g * KMAX + m];
    __syncthreads();

    if (t >= 64) return;
    u64 remv = 0ull;
    for (int w = 0; w < W; ++w) {
        int r0 = w << 6;
        int rend = Kc - r0; if (rend > 64) rend = 64;
        u64 curw = __shfl(remv, w);
        u64 kb = 0ull;
        for (int b0 = 0; b0 < rend; b0 += 8) {
            int n = rend - b0; if (n > 8) n = 8;
            u64 mrow[8], dg[8];
            #pragma unroll
            for (int j = 0; j < 8; ++j) {
                int rr = r0 + b0 + ((j < n) ? j : 0);
                mrow[j] = maskm[rr * MSTRIDE + lane];   /* +64 pad covers overrun */
                dg[j]   = maskm[rr * MSTRIDE + w];      /* uniform: broadcast */
            }
            #pragma unroll
            for (int j = 0; j < 8; ++j) {
                if (j < n) {
                    int b = b0 + j;
                    u64 km = ((curw >> b) & 1ull) ? 0ull : ~0ull;
                    curw |= dg[j] & km;
                    remv |= mrow[j] & km;
                    kb |= km & (1ull << b);
                }
            }
        }
        if (lane < rend)
            out[(int)grank[r0 + lane] * 6 + 5] = ((kb >> lane) & 1ull) ? 1.0f : 0.0f;
    }
}

extern "C" void kernel_launch(void* const* d_in, const int* in_sizes, int n_in,
                              void* d_out, int out_size, void* d_ws, size_t ws_size,
                              hipStream_t stream) {
    const float*  probs    = (const float*)d_in[0];
    const float4* deltas4  = (const float4*)d_in[1];
    const float4* anchors4 = (const float4*)d_in[2];
    int n_prop = in_sizes[1] / 4;   /* 522240 */
    int n_anch = in_sizes[2] / 4;   /* 65280  */

    char* ws = (char*)d_ws;
    u32* ctr      = (u32*)(ws + CTR_OFF);
    u32* fineh    = (u32*)(ws + FINEH_OFF);
    u32* bcnt     = (u32*)(ws + BCNT_OFF);
    u32* gbits    = (u32*)(ws + GBITS_OFF);
    u64* cand     = (u64*)(ws + CAND_OFF);
    float4* boxr  = (float4*)(ws + BOXR_OFF);
    u32* kg       = (u32*)(ws + KG_OFF);
    u32* grankg   = (u32*)(ws + GRANKG_OFF);
    float4* boxg  = (float4*)(ws + BOXG_OFF);
    float* areag  = (float*)(ws + AREAG_OFF);
    u64* maskg    = (u64*)(ws + MASKG_OFF);
    u32* base     = (u32*)(ws + BASE_OFF);
    u32* partials = (u32*)(ws + PART_OFF);
    float* out    = (float*)d_out;

    hipMemsetAsync(ws + FINEH_OFF, 0, ZERO_LEN, stream);
    hist_kernel<<<NHB, 1024, 0, stream>>>((const float4*)probs, fineh, partials, n_prop);
    pivot_kernel<<<1, 1024, 0, stream>>>(fineh, partials, ctr, base);
    scatter_kernel<<<256, 256, 0, stream>>>((const float4*)probs, ctr, base, bcnt,
                                            cand, n_prop);
    rankdecode_kernel<<<CANDMAX / 256, 256, 0, stream>>>(cand, ctr, base, bcnt,
                                                         deltas4, anchors4,
                                                         boxr, gbits, out, n_anch);
    prep_kernel<<<NGRP, 512, 0, stream>>>(gbits, boxr, kg, grankg, boxg, areag);
    mask_kernel<<<dim3(MTILE, NGRP), 64, 0, stream>>>(kg, boxg, areag, maskg);
    greedy_kernel<<<NGRP, 512, 0, stream>>>(kg, grankg, maskg, out);
}